// Round 13
// baseline (454.525 us; speedup 1.0000x reference)
//
#include <hip/hip_runtime.h>

#define LK   50      // look_back
#define NOUT 3
#define FF   64      // feature_num
#define BB   2048    // batch
#define BT   8       // batch rows per workgroup
#define NWG  (BB/BT) // 256 workgroups
#define NTHR 1024    // 16 waves

typedef unsigned short u16;
typedef unsigned int   u32;
typedef __attribute__((ext_vector_type(8))) short short8;
typedef __attribute__((ext_vector_type(4))) float f32x4;

#define MFMA16(a,b,c) __builtin_amdgcn_mfma_f32_16x16x32_bf16(a,b,c,0,0,0)
// ring geometry (u16 units): x tile t at 1152*t (16 rows x 72); enc row rt at 136*rt
#define XP   72
#define EP   136

// pre-converted bf16 weight buffers (device globals; rewritten every launch)
__device__ u16 g_awT [(size_t)LK*64*192];  // attn_w^T, [t][c][k]  k:[xt(64)|h(128)]
__device__ u16 g_eW  [512*192];            // enc LSTM, [gate][k]
__device__ u16 g_dW  [512*384];            // dec LSTM, [gate][k]  k:[ctx|h|h]
__device__ u16 g_ddwT[NOUT*128*256];       // dd_w^T,   [s][n][k]
__device__ u16 g_fcwT[NOUT*64*128];        // fc_w^T,   [s][n][k]

__device__ __forceinline__ float sigf(float x) { return 1.0f / (1.0f + __expf(-x)); }
__device__ __forceinline__ float tanhff(float x) { return 1.0f - 2.0f / (__expf(2.0f * x) + 1.0f); }
__device__ __forceinline__ u16 f2b(float f) {
    union { float f; u32 u; } v; v.f = f;
    u32 r = v.u + 0x7fffu + ((v.u >> 16) & 1u);
    return (u16)(r >> 16);
}
__device__ __forceinline__ float b2f(u16 h) {
    union { u32 u; float f; } v; v.u = ((u32)h) << 16; return v.f;
}

// merged convert dispatch (verified R12): blocks 0..49 transpose awT, rest weights
__global__ __launch_bounds__(256)
void convert_kernel(const float* __restrict__ aw,
                    const float* __restrict__ eWih, const float* __restrict__ eWhh,
                    const float* __restrict__ dWih, const float* __restrict__ dWhh,
                    const float* __restrict__ ddw,  const float* __restrict__ fcw)
{
    __shared__ u16 tile[192*66];
    if (blockIdx.x < LK) {
        const int t = blockIdx.x, tid = threadIdx.x;
        for (int i = tid; i < 192*64; i += 256) {
            int k = i >> 6, c = i & 63;
            tile[k*66 + c] = f2b(aw[(size_t)t*12288 + i]);
        }
        __syncthreads();
        u32* dst = (u32*)g_awT + (size_t)t * 6144;
        for (int j = tid; j < 6144; j += 256) {
            int c = j / 96, w = j % 96;
            dst[j] = (u32)tile[(2*w)*66 + c] | ((u32)tile[(2*w+1)*66 + c] << 16);
        }
        return;
    }
    const int gid = (blockIdx.x - LK) * blockDim.x + threadIdx.x;
    const int stride = (gridDim.x - LK) * blockDim.x;
    for (int i = gid; i < 512*192; i += stride) {
        int j = i / 192, k = i % 192;
        g_eW[i] = f2b(k < 64 ? eWih[j*64 + k] : eWhh[j*128 + (k-64)]);
    }
    for (int i = gid; i < 512*384; i += stride) {
        int j = i / 384, k = i % 384;
        g_dW[i] = f2b(k < 256 ? dWih[j*256 + k] : dWhh[j*128 + (k-256)]);
    }
    for (int i = gid; i < NOUT*256*128; i += stride) {
        int s = i / 32768, rm = i % 32768, k = rm / 128, n = rm % 128;
        g_ddwT[(size_t)s*32768 + n*256 + k] = f2b(ddw[i]);
    }
    for (int i = gid; i < NOUT*128*64; i += stride) {
        int s = i / 8192, rm = i % 8192, k = rm / 64, n = rm % 64;
        g_fcwT[(size_t)s*8192 + n*128 + k] = f2b(fcw[i]);
    }
}

__global__ __launch_bounds__(NTHR, 4)
void darnn_kernel(const float* __restrict__ x,
                  const float* __restrict__ ab,
                  const float* __restrict__ ebih, const float* __restrict__ ebhh,
                  const float* __restrict__ dbih, const float* __restrict__ dbhh,
                  const float* __restrict__ ddb,
                  const float* __restrict__ dlw,  const float* __restrict__ dlb,
                  const float* __restrict__ fcb,
                  const float* __restrict__ ow,   const float* __restrict__ ob,
                  float* __restrict__ out)
{
    // ring: x tiles (consumed forward) overwritten by enc rows (written forward)
    __shared__ __align__(16) u16 s_ring[57600];     // 115200 B
    __shared__ __align__(16) u32 s_pool[4288];      //  17152 B (enc/dec overlay)
    __shared__ float s_c[8][128];                   //   4096 B
    __shared__ float s_g[512][9];                   //  18432 B
    __shared__ float s_ebias[512];                  //   2048 B
    __shared__ float s_dbias[512];                  //   2048 B
    // encoder overlay
    u16  (*s_xin)[XP]   = (u16 (*)[XP])(s_pool);            // 16 rows, 8-15 stay zero
    u16  (*s_h)[144]    = (u16 (*)[144])(s_pool + 576);     // hi rows 0-7, lo rows 8-15
    float(*s_e)[64]     = (float (*)[64])(s_pool + 1728);
    // decoder overlay
    u16  (*s_Adec)[272] = (u16 (*)[272])(s_pool);           // [ctx|h], lo rows 8-15
    float(*s_spart)[400]= (float (*)[400])(s_pool + 2176);
    float(*s_y1)[64]    = (float (*)[64])(s_pool + 3776);
    // decoder scratch in ring tail (enc occupies u16 [0, 54400))
    float(*s_hp)[128]   = (float (*)[128])(s_ring + 54400); // 4096 B
    float(*s_alpha)[64] = (float (*)[64])(s_ring + 56448);  // 2048 B

    const int tid  = threadIdx.x;
    const int b0   = blockIdx.x * BT;
    const int wv   = tid >> 6;
    const int lane = tid & 63;
    const int quad = lane >> 4;
    const int l16  = lane & 15;
    const int n0   = wv * 32;
    const int f0   = (wv & 3) * 16 + l16;   // attn col for waves 0-3

    // ---- preamble ----
    for (int i = tid; i < 28800; i += NTHR) ((u32*)s_ring)[i] = 0;
    for (int i = tid; i < 4288; i += NTHR) s_pool[i] = 0;
    (&s_c[0][0])[tid] = 0.0f;
    if (tid < 512) { s_ebias[tid] = ebih[tid] + ebhh[tid]; s_dbias[tid] = dbih[tid] + dbhh[tid]; }
    __syncthreads();
    // bulk-stage ALL x into ring (bf16, rows 8-15 zero from memset)
    for (int i = tid; i < 12800; i += NTHR) {
        int r = i / 1600, j = i - r * 1600;          // j in float2 units within row
        float2 v = *(const float2*)(x + (size_t)(b0 + r) * 3200 + 2 * j);
        int t0 = j >> 5, f2 = j & 31;
        ((u32*)s_ring)[t0 * 576 + r * 36 + f2] = (u32)f2b(v.x) | ((u32)f2b(v.y) << 16);
    }
    // pin eW B-set: 2 tiles x 6 chunks = 48 VGPRs
    short8 wf[12];
#pragma unroll
    for (int nn = 0; nn < 2; ++nn)
#pragma unroll
        for (int uc = 0; uc < 6; ++uc)
            wf[nn*6+uc] = *(const short8*)(g_eW + (size_t)(n0 + nn*16 + l16) * 192 + uc*32 + quad*8);
    // attn B-frags + bias for t=0
    short8 bfr[6];
    float abv = 0.0f;
    if (wv < 4) {
        const u16* bp = g_awT + f0 * 192 + quad * 8;
#pragma unroll
        for (int uc = 0; uc < 6; ++uc) bfr[uc] = *(const short8*)(bp + uc*32);
        abv = ab[f0];
    }
    __syncthreads();

    // ================= ENCODER: 50 steps, 4 barriers, drain-free =================
#pragma unroll 1
    for (int t = 0; t < LK; ++t) {
        f32x4 ga0 = {0.f,0.f,0.f,0.f}, ga1 = {0.f,0.f,0.f,0.f};  // persist P1->P3
        short8 bnext[6]; float abn = 0.0f;

        // --- P1: gate h-part (all 16 waves) + attention e (waves 0-3) ---
        {
            short8 hv[4];
#pragma unroll
            for (int c2 = 0; c2 < 4; ++c2) hv[c2] = *(const short8*)&s_h[l16][c2*32 + quad*8];
            if (wv < 4) {
                const u16* xb = s_ring + t*1152 + l16*XP + quad*8;
                f32x4 acc = {0.f,0.f,0.f,0.f};
                acc = MFMA16(*(const short8*)xb,        bfr[0], acc);
                acc = MFMA16(*(const short8*)(xb + 32), bfr[1], acc);
#pragma unroll
                for (int c2 = 0; c2 < 4; ++c2) acc = MFMA16(hv[c2], bfr[2 + c2], acc);
                float ev[4];
#pragma unroll
                for (int rg = 0; rg < 4; ++rg) ev[rg] = acc[rg] + __shfl_xor(acc[rg], 32, 64);
                if (quad < 2) {
#pragma unroll
                    for (int rg = 0; rg < 4; ++rg) s_e[quad*4 + rg][f0] = ev[rg] + abv;
                }
            }
#pragma unroll
            for (int c2 = 0; c2 < 4; ++c2) {
                ga0 = MFMA16(hv[c2], wf[2 + c2], ga0);
                ga1 = MFMA16(hv[c2], wf[8 + c2], ga1);
            }
        }
        __syncthreads();

        // --- P2: softmax, max-free; xin = smax(tanh(e)) * x(t) ---
        if (tid < 512) {
            const int r = tid >> 6;
            float ex = __expf(tanhff(s_e[r][lane]));
            float sm = ex;
#pragma unroll
            for (int m = 1; m < 64; m <<= 1) sm += __shfl_xor(sm, m, 64);
            s_xin[r][lane] = f2b(ex / sm * b2f(s_ring[t*1152 + r*XP + lane]));
        }
        __syncthreads();

        // --- P3: prefetch next awT/ab (drained by P3 barrier) + xin gates ---
        if (wv < 4) {
            const int tn = (t + 1 < LK) ? t + 1 : LK - 1;
            const u16* bp = g_awT + (size_t)tn * 12288 + f0 * 192 + quad * 8;
#pragma unroll
            for (int uc = 0; uc < 6; ++uc) bnext[uc] = *(const short8*)(bp + uc*32);
            abn = ab[tn * FF + f0];
        }
        {
            short8 xv0 = *(const short8*)&s_xin[l16][quad*8];
            short8 xv1 = *(const short8*)&s_xin[l16][32 + quad*8];
            ga0 = MFMA16(xv0, wf[0], ga0); ga0 = MFMA16(xv1, wf[1], ga0);
            ga1 = MFMA16(xv0, wf[6], ga1); ga1 = MFMA16(xv1, wf[7], ga1);
            float v0[4], v1[4];
#pragma unroll
            for (int rg = 0; rg < 4; ++rg) {
                v0[rg] = ga0[rg] + __shfl_xor(ga0[rg], 32, 64);
                v1[rg] = ga1[rg] + __shfl_xor(ga1[rg], 32, 64);
            }
            if (quad < 2) {
#pragma unroll
                for (int rg = 0; rg < 4; ++rg) {
                    int r = quad*4 + rg;
                    s_g[n0 + l16][r]      = v0[rg];
                    s_g[n0 + 16 + l16][r] = v1[rg];
                }
            }
        }
        __syncthreads();

        // --- P4: combine + state update + enc->ring (t-major) ---
        {
            const int u = tid & 127, r = tid >> 7;
            float gi = s_g[u][r]       + s_ebias[u];
            float gf = s_g[128 + u][r] + s_ebias[128 + u];
            float gg = s_g[256 + u][r] + s_ebias[256 + u];
            float go = s_g[384 + u][r] + s_ebias[384 + u];
            float c = sigf(gf) * s_c[r][u] + sigf(gi) * tanhff(gg);
            float h = sigf(go) * tanhff(c);
            s_c[r][u] = c;
            u16 hi = f2b(h);
            s_h[r][u]     = hi;
            s_h[r + 8][u] = f2b(h - b2f(hi));
            s_ring[(t*8 + r) * EP + u] = hi;
        }
        if (wv < 4) {
#pragma unroll
            for (int uc = 0; uc < 6; ++uc) bfr[uc] = bnext[uc];
            abv = abn;
        }
        __syncthreads();
    }

    // ================= DECODER: 3 steps, enc from ring =================
    for (int i = tid; i < 4288; i += NTHR) s_pool[i] = 0;
    (&s_c[0][0])[tid] = 0.0f;
    __syncthreads();

#pragma unroll 1
    for (int s = 0; s < NOUT; ++s) {
        // D1: hpart = h_de @ ddw[128:,:] + ddb (8 waves, K=128 lo-folded)
        if (wv < 8) {
            const int n = wv * 16 + l16;
            f32x4 acc = {0.f,0.f,0.f,0.f};
            const u16* bp = g_ddwT + s * 32768 + n * 256 + 128 + quad * 8;
#pragma unroll
            for (int c = 0; c < 4; ++c) {
                short8 av = *(const short8*)&s_Adec[l16][128 + c*32 + quad*8];
                acc = MFMA16(av, *(const short8*)(bp + c*32), acc);
            }
            float vv[4];
#pragma unroll
            for (int rg = 0; rg < 4; ++rg) vv[rg] = acc[rg] + __shfl_xor(acc[rg], 32, 64);
            const float db = ddb[s * 128 + n];
            if (quad < 2) {
#pragma unroll
                for (int rg = 0; rg < 4; ++rg) s_hp[quad*4 + rg][n] = vv[rg] + db;
            }
        }
        __syncthreads();

        // D2: score GEMM [400,128-K] x [128,128], A = enc rows (t-major)
        {
            const int np = wv & 3, mq = wv >> 2, nb0 = np * 32;
            short8 bfr2[8];
            const u16* bp = g_ddwT + s * 32768 + (nb0 + l16) * 256 + quad * 8;
#pragma unroll
            for (int nn = 0; nn < 2; ++nn)
#pragma unroll
                for (int ks = 0; ks < 4; ++ks)
                    bfr2[nn*4+ks] = *(const short8*)(bp + nn*4096 + ks*32);
            const float dl0 = dlw[s*128 + nb0 + l16];
            const float dl1 = dlw[s*128 + nb0 + 16 + l16];
#pragma unroll 1
            for (int mt = mq; mt < 25; mt += 4) {
                const u16* ap = s_ring + (mt*16 + l16) * EP + quad * 8;
                f32x4 a0 = {0.f,0.f,0.f,0.f}, a1 = {0.f,0.f,0.f,0.f};
#pragma unroll
                for (int c = 0; c < 4; ++c) {
                    short8 av = *(const short8*)(ap + c*32);
                    a0 = MFMA16(av, bfr2[c],     a0);
                    a1 = MFMA16(av, bfr2[4 + c], a1);
                }
#pragma unroll
                for (int rg = 0; rg < 4; ++rg) {
                    int rt = mt*16 + quad*4 + rg;
                    int r  = rt & 7;                       // t-major
                    float v = tanhff(a0[rg] + s_hp[r][nb0 + l16]) * dl0
                            + tanhff(a1[rg] + s_hp[r][nb0 + 16 + l16]) * dl1;
                    v += __shfl_xor(v, 1, 64); v += __shfl_xor(v, 2, 64);
                    v += __shfl_xor(v, 4, 64); v += __shfl_xor(v, 8, 64);
                    if (l16 == 0) s_spart[np][rt] = v;
                }
            }
        }
        __syncthreads();

        // D3: softmax over t, max-free (rt = lane*8 + r, t-major)
        if (tid < 512) {
            const int r = tid >> 6;
            float ex = 0.0f;
            if (lane < LK) {
                int rt = lane * 8 + r;
                ex = __expf(s_spart[0][rt] + s_spart[1][rt] +
                            s_spart[2][rt] + s_spart[3][rt] + dlb[s]);
            }
            float sm = ex;
#pragma unroll
            for (int m = 1; m < 64; m <<= 1) sm += __shfl_xor(sm, m, 64);
            if (lane < LK) s_alpha[r][lane] = ex / sm;
        }
        __syncthreads();

        // D4: ctx = sum_t alpha * enc (fp32); store hi/lo rows
        {
            const int jd = tid & 127, r = tid >> 7;
            const u16* ep = s_ring + r * EP + jd;
            float a = 0.0f;
#pragma unroll 10
            for (int tt = 0; tt < LK; ++tt) a += s_alpha[r][tt] * b2f(ep[tt * (8*EP)]);
            u16 hi = f2b(a);
            s_Adec[r][jd]     = hi;
            s_Adec[r + 8][jd] = f2b(a - b2f(hi));
        }
        __syncthreads();

        // D5: decoder LSTM gates, K=384 lo-folded, B bf16 (g_dW)
        {
            const int nd0 = wv * 32;
            f32x4 a0 = {0.f,0.f,0.f,0.f}, a1 = {0.f,0.f,0.f,0.f};
            const u16* bp0 = g_dW + (nd0 + l16) * 384 + quad * 8;
            const u16* bp1 = bp0 + 16 * 384;
#pragma unroll
            for (int c = 0; c < 12; ++c) {
                const int g = c >> 2, o = (c & 3) * 32;
                const int aoff = (g == 0 ? 0 : 128) + o;
                const int boff = g * 128 + o;
                short8 av = *(const short8*)&s_Adec[l16][aoff + quad*8];
                a0 = MFMA16(av, *(const short8*)(bp0 + boff), a0);
                a1 = MFMA16(av, *(const short8*)(bp1 + boff), a1);
            }
            float v0[4], v1[4];
#pragma unroll
            for (int rg = 0; rg < 4; ++rg) {
                v0[rg] = a0[rg] + __shfl_xor(a0[rg], 32, 64);
                v1[rg] = a1[rg] + __shfl_xor(a1[rg], 32, 64);
            }
            if (quad < 2) {
#pragma unroll
                for (int rg = 0; rg < 4; ++rg) {
                    int r = quad*4 + rg;
                    s_g[nd0 + l16][r]      = v0[rg];
                    s_g[nd0 + 16 + l16][r] = v1[rg];
                }
            }
        }
        __syncthreads();

        // D6: gate combine + state update (hi/lo rows)
        {
            const int u = tid & 127, r = tid >> 7;
            float gi = s_g[u][r]       + s_dbias[u];
            float gf = s_g[128 + u][r] + s_dbias[128 + u];
            float gg = s_g[256 + u][r] + s_dbias[256 + u];
            float go = s_g[384 + u][r] + s_dbias[384 + u];
            float c = sigf(gf) * s_c[r][u] + sigf(gi) * tanhff(gg);
            float h = sigf(go) * tanhff(c);
            s_c[r][u] = c;
            u16 hi = f2b(h);
            s_Adec[r][128 + u]     = hi;
            s_Adec[r + 8][128 + u] = f2b(h - b2f(hi));
        }
        __syncthreads();

        // D7: head y1 = tanh(h @ fc_w + fc_b) (4 waves, K=128 lo-folded)
        if (wv < 4) {
            const int n = wv * 16 + l16;
            f32x4 acc = {0.f,0.f,0.f,0.f};
            const u16* bp = g_fcwT + s * 8192 + n * 128 + quad * 8;
#pragma unroll
            for (int c = 0; c < 4; ++c) {
                short8 av = *(const short8*)&s_Adec[l16][128 + c*32 + quad*8];
                acc = MFMA16(av, *(const short8*)(bp + c*32), acc);
            }
            float vv[4];
#pragma unroll
            for (int rg = 0; rg < 4; ++rg) vv[rg] = acc[rg] + __shfl_xor(acc[rg], 32, 64);
            const float fb = fcb[s * 64 + n];
            if (quad < 2) {
#pragma unroll
                for (int rg = 0; rg < 4; ++rg) s_y1[quad*4 + rg][n] = tanhff(vv[rg] + fb);
            }
        }
        __syncthreads();

        // D8: out = sigmoid(y1 @ out_w + out_b)
        if (tid < 512) {
            const int r = tid >> 6;
            float v = s_y1[r][lane] * ow[s * 64 + lane];
#pragma unroll
            for (int m = 1; m < 64; m <<= 1) v += __shfl_xor(v, m, 64);
            if (lane == 0) out[(b0 + r) * NOUT + s] = sigf(v + ob[s]);
        }
        __syncthreads();
    }
}

extern "C" void kernel_launch(void* const* d_in, const int* in_sizes, int n_in,
                              void* d_out, int out_size, void* d_ws, size_t ws_size,
                              hipStream_t stream) {
    const float* x    = (const float*)d_in[0];
    const float* eWih = (const float*)d_in[1];
    const float* eWhh = (const float*)d_in[2];
    const float* ebih = (const float*)d_in[3];
    const float* ebhh = (const float*)d_in[4];
    const float* aw   = (const float*)d_in[5];
    const float* ab   = (const float*)d_in[6];
    const float* dWih = (const float*)d_in[7];
    const float* dWhh = (const float*)d_in[8];
    const float* dbih = (const float*)d_in[9];
    const float* dbhh = (const float*)d_in[10];
    const float* ddw  = (const float*)d_in[11];
    const float* ddb  = (const float*)d_in[12];
    const float* dlw  = (const float*)d_in[13];
    const float* dlb  = (const float*)d_in[14];
    const float* fcw  = (const float*)d_in[15];
    const float* fcb  = (const float*)d_in[16];
    const float* ow   = (const float*)d_in[17];
    const float* ob   = (const float*)d_in[18];
    float* out = (float*)d_out;

    convert_kernel<<<LK + 512, 256, 0, stream>>>(aw, eWih, eWhh, dWih, dWhh, ddw, fcw);
    darnn_kernel<<<NWG, NTHR, 0, stream>>>(x, ab, ebih, ebhh, dbih, dbhh, ddb,
                                           dlw, dlb, fcb, ow, ob, out);
}

// Round 14
// 361.176 us; speedup vs baseline: 1.2585x; 1.2585x over previous
//
#include <hip/hip_runtime.h>

#define LK   50      // look_back
#define NOUT 3
#define FF   64      // feature_num
#define BB   2048    // batch
#define BT   8       // batch rows per workgroup
#define NWG  (BB/BT) // 256 workgroups
#define NTHR 1024    // 16 waves

typedef unsigned short u16;
typedef unsigned int   u32;
typedef __attribute__((ext_vector_type(8))) short short8;
typedef __attribute__((ext_vector_type(4))) float f32x4;

#define MFMA16(a,b,c) __builtin_amdgcn_mfma_f32_16x16x32_bf16(a,b,c,0,0,0)
// ring geometry (u16): x tile t at 1152*t (16 rows x 72); enc row rt=t*8+r at 136*rt
#define XP   72
#define EP   136

// pre-converted bf16 weight buffers (device globals; rewritten every launch)
__device__ u16 g_awT [(size_t)LK*64*192];  // attn_w^T, [t][c][k]  k:[xt(64)|h(128)]
__device__ u16 g_eW  [512*192];            // enc LSTM, [gate][k]
__device__ u16 g_dW  [512*384];            // dec LSTM, [gate][k]  k:[ctx|h|h]
__device__ u16 g_ddwT[NOUT*128*256];       // dd_w^T,   [s][n][k]
__device__ u16 g_fcwT[NOUT*64*128];        // fc_w^T,   [s][n][k]

__device__ __forceinline__ float sigf(float x) { return 1.0f / (1.0f + __expf(-x)); }
__device__ __forceinline__ float tanhff(float x) { return 1.0f - 2.0f / (__expf(2.0f * x) + 1.0f); }
__device__ __forceinline__ u16 f2b(float f) {
    union { float f; u32 u; } v; v.f = f;
    u32 r = v.u + 0x7fffu + ((v.u >> 16) & 1u);
    return (u16)(r >> 16);
}
__device__ __forceinline__ float b2f(u16 h) {
    union { u32 u; float f; } v; v.u = ((u32)h) << 16; return v.f;
}

// merged convert dispatch (verified R12): blocks 0..49 transpose awT, rest weights
__global__ __launch_bounds__(256)
void convert_kernel(const float* __restrict__ aw,
                    const float* __restrict__ eWih, const float* __restrict__ eWhh,
                    const float* __restrict__ dWih, const float* __restrict__ dWhh,
                    const float* __restrict__ ddw,  const float* __restrict__ fcw)
{
    __shared__ u16 tile[192*66];
    if (blockIdx.x < LK) {
        const int t = blockIdx.x, tid = threadIdx.x;
        for (int i = tid; i < 192*64; i += 256) {
            int k = i >> 6, c = i & 63;
            tile[k*66 + c] = f2b(aw[(size_t)t*12288 + i]);
        }
        __syncthreads();
        u32* dst = (u32*)g_awT + (size_t)t * 6144;
        for (int j = tid; j < 6144; j += 256) {
            int c = j / 96, w = j % 96;
            dst[j] = (u32)tile[(2*w)*66 + c] | ((u32)tile[(2*w+1)*66 + c] << 16);
        }
        return;
    }
    const int gid = (blockIdx.x - LK) * blockDim.x + threadIdx.x;
    const int stride = (gridDim.x - LK) * blockDim.x;
    for (int i = gid; i < 512*192; i += stride) {
        int j = i / 192, k = i % 192;
        g_eW[i] = f2b(k < 64 ? eWih[j*64 + k] : eWhh[j*128 + (k-64)]);
    }
    for (int i = gid; i < 512*384; i += stride) {
        int j = i / 384, k = i % 384;
        g_dW[i] = f2b(k < 256 ? dWih[j*256 + k] : dWhh[j*128 + (k-256)]);
    }
    for (int i = gid; i < NOUT*256*128; i += stride) {
        int s = i / 32768, rm = i % 32768, k = rm / 128, n = rm % 128;
        g_ddwT[(size_t)s*32768 + n*256 + k] = f2b(ddw[i]);
    }
    for (int i = gid; i < NOUT*128*64; i += stride) {
        int s = i / 8192, rm = i % 8192, k = rm / 64, n = rm % 64;
        g_fcwT[(size_t)s*8192 + n*128 + k] = f2b(fcw[i]);
    }
}

__global__ __launch_bounds__(NTHR, 4)
void darnn_kernel(const float* __restrict__ x,
                  const float* __restrict__ ab,
                  const float* __restrict__ ebih, const float* __restrict__ ebhh,
                  const float* __restrict__ dbih, const float* __restrict__ dbhh,
                  const float* __restrict__ ddb,
                  const float* __restrict__ dlw,  const float* __restrict__ dlb,
                  const float* __restrict__ fcb,
                  const float* __restrict__ ow,   const float* __restrict__ ob,
                  float* __restrict__ out)
{
    // ring: x tiles (consumed forward) overwritten by enc rows (written forward)
    __shared__ __align__(16) u16 s_ring[57600];     // 115200 B
    __shared__ __align__(16) u32 s_pool[4288];      //  17152 B (enc/dec overlay)
    __shared__ float s_c[8][128];                   //   4096 B
    __shared__ float s_g[512][9];                   //  18432 B
    __shared__ float s_ebias[512];                  //   2048 B
    __shared__ float s_dbias[512];                  //   2048 B
    // encoder overlay
    u16  (*s_xin)[XP]    = (u16 (*)[XP])(s_pool);           // 16 rows, 8-15 stay zero
    u16  (*s_h)[144]     = (u16 (*)[144])(s_pool + 576);    // hi rows 0-7, lo rows 8-15
    float(*s_e2)[8][64]  = (float (*)[8][64])(s_pool + 1728); // attn K-split partials
    // decoder overlay
    u16  (*s_Adec)[272]  = (u16 (*)[272])(s_pool);          // [ctx|h], lo rows 8-15
    float(*s_spart)[400] = (float (*)[400])(s_pool + 2176);
    float(*s_y1)[64]     = (float (*)[64])(s_pool + 3776);
    // decoder scratch in ring tail (enc occupies u16 [0, 54400))
    float(*s_hp)[128]    = (float (*)[128])(s_ring + 54400);
    float(*s_alpha)[64]  = (float (*)[64])(s_ring + 56448);

    const int tid  = threadIdx.x;
    const int b0   = blockIdx.x * BT;
    const int wv   = tid >> 6;
    const int lane = tid & 63;
    const int quad = lane >> 4;
    const int l16  = lane & 15;
    const int n0   = wv * 32;

    // ---- preamble ----
    for (int i = tid; i < 28800; i += NTHR) ((u32*)s_ring)[i] = 0;
    for (int i = tid; i < 4288; i += NTHR) s_pool[i] = 0;
    (&s_c[0][0])[tid] = 0.0f;
    if (tid < 512) { s_ebias[tid] = ebih[tid] + ebhh[tid]; s_dbias[tid] = dbih[tid] + dbhh[tid]; }
    __syncthreads();
    // bulk-stage ALL x into ring (bf16; rows 8-15 zero from memset)
    for (int i = tid; i < 12800; i += NTHR) {
        int r = i / 1600, j = i - r * 1600;          // j in float2 units within row
        float2 v = *(const float2*)(x + (size_t)(b0 + r) * 3200 + 2 * j);
        int t0 = j >> 5, f2 = j & 31;
        ((u32*)s_ring)[t0 * 576 + r * 36 + f2] = (u32)f2b(v.x) | ((u32)f2b(v.y) << 16);
    }
    // pin eW B-set: 2 tiles x 6 chunks = 48 VGPRs
    short8 wf[12];
#pragma unroll
    for (int nn = 0; nn < 2; ++nn)
#pragma unroll
        for (int uc = 0; uc < 6; ++uc)
            wf[nn*6+uc] = *(const short8*)(g_eW + (size_t)(n0 + nn*16 + l16) * 192 + uc*32 + quad*8);
    __syncthreads();

    // ================= ENCODER: 50 steps, 4 barriers =================
#pragma unroll 1
    for (int t = 0; t < LK; ++t) {
        float v0[4], v1[4];   // reduced h-gate partials, carried P1->P3 (8 VGPRs only)

        // --- P1: h-gates on ALL 16 waves (zero loads) + attn K-split on waves 0-7 ---
        {
            short8 hv[4];
#pragma unroll
            for (int c2 = 0; c2 < 4; ++c2) hv[c2] = *(const short8*)&s_h[l16][c2*32 + quad*8];
            f32x4 ga0 = {0.f,0.f,0.f,0.f}, ga1 = {0.f,0.f,0.f,0.f};
#pragma unroll
            for (int c2 = 0; c2 < 4; ++c2) {
                ga0 = MFMA16(hv[c2], wf[2 + c2], ga0);
                ga1 = MFMA16(hv[c2], wf[8 + c2], ga1);
            }
#pragma unroll
            for (int rg = 0; rg < 4; ++rg) {
                v0[rg] = ga0[rg] + __shfl_xor(ga0[rg], 32, 64);
                v1[rg] = ga1[rg] + __shfl_xor(ga1[rg], 32, 64);
            }
            if (wv < 8) {
                const int kh = wv >> 2;                 // K-half: 0 -> chunks 0-2, 1 -> 3-5
                const int fa = (wv & 3) * 16 + l16;
                const u16* bp = g_awT + (size_t)t * 12288 + fa * 192 + kh * 96 + quad * 8;
                short8 b0 = *(const short8*)bp;
                short8 b1 = *(const short8*)(bp + 32);
                short8 b2 = *(const short8*)(bp + 64);
                f32x4 acc = {0.f,0.f,0.f,0.f};
                if (kh == 0) {
                    const u16* xb = s_ring + t*1152 + l16*XP + quad*8;
                    acc = MFMA16(*(const short8*)xb,        b0, acc);
                    acc = MFMA16(*(const short8*)(xb + 32), b1, acc);
                    acc = MFMA16(hv[0], b2, acc);
                } else {
                    acc = MFMA16(hv[1], b0, acc);
                    acc = MFMA16(hv[2], b1, acc);
                    acc = MFMA16(hv[3], b2, acc);
                }
                float ev[4];
#pragma unroll
                for (int rg = 0; rg < 4; ++rg) ev[rg] = acc[rg] + __shfl_xor(acc[rg], 32, 64);
                if (quad < 2) {
#pragma unroll
                    for (int rg = 0; rg < 4; ++rg) s_e2[kh][quad*4 + rg][fa] = ev[rg];
                }
            }
        }
        __syncthreads();

        // --- P2: softmax, max-free; xin = smax(tanh(e0+e1+ab)) * x(t) ---
        if (tid < 512) {
            const int r = tid >> 6;
            float e = tanhff(s_e2[0][r][lane] + s_e2[1][r][lane] + ab[t*FF + lane]);
            float ex = __expf(e);
            float sm = ex;
#pragma unroll
            for (int m = 1; m < 64; m <<= 1) sm += __shfl_xor(sm, m, 64);
            s_xin[r][lane] = f2b(ex / sm * b2f(s_ring[t*1152 + r*XP + lane]));
        }
        __syncthreads();

        // --- P3: xin-gates (4 MFMA) + carried h-part -> s_g ---
        {
            short8 xv0 = *(const short8*)&s_xin[l16][quad*8];
            short8 xv1 = *(const short8*)&s_xin[l16][32 + quad*8];
            f32x4 a0 = {0.f,0.f,0.f,0.f}, a1 = {0.f,0.f,0.f,0.f};
            a0 = MFMA16(xv0, wf[0], a0); a0 = MFMA16(xv1, wf[1], a0);
            a1 = MFMA16(xv0, wf[6], a1); a1 = MFMA16(xv1, wf[7], a1);
            float w0[4], w1[4];
#pragma unroll
            for (int rg = 0; rg < 4; ++rg) {
                w0[rg] = v0[rg] + a0[rg] + __shfl_xor(a0[rg], 32, 64);
                w1[rg] = v1[rg] + a1[rg] + __shfl_xor(a1[rg], 32, 64);
            }
            if (quad < 2) {
#pragma unroll
                for (int rg = 0; rg < 4; ++rg) {
                    int r = quad*4 + rg;
                    s_g[n0 + l16][r]      = w0[rg];
                    s_g[n0 + 16 + l16][r] = w1[rg];
                }
            }
        }
        __syncthreads();

        // --- P4: combine + state update + enc->ring (t-major) ---
        {
            const int u = tid & 127, r = tid >> 7;
            float gi = s_g[u][r]       + s_ebias[u];
            float gf = s_g[128 + u][r] + s_ebias[128 + u];
            float gg = s_g[256 + u][r] + s_ebias[256 + u];
            float go = s_g[384 + u][r] + s_ebias[384 + u];
            float c = sigf(gf) * s_c[r][u] + sigf(gi) * tanhff(gg);
            float h = sigf(go) * tanhff(c);
            s_c[r][u] = c;
            u16 hi = f2b(h);
            s_h[r][u]     = hi;
            s_h[r + 8][u] = f2b(h - b2f(hi));
            s_ring[(t*8 + r) * EP + u] = hi;
        }
        __syncthreads();
    }

    // ================= DECODER: 3 steps, enc from ring (R13-verified) =================
    for (int i = tid; i < 4288; i += NTHR) s_pool[i] = 0;
    (&s_c[0][0])[tid] = 0.0f;
    __syncthreads();

#pragma unroll 1
    for (int s = 0; s < NOUT; ++s) {
        // D1: hpart = h_de @ ddw[128:,:] + ddb (8 waves, K=128 lo-folded)
        if (wv < 8) {
            const int n = wv * 16 + l16;
            f32x4 acc = {0.f,0.f,0.f,0.f};
            const u16* bp = g_ddwT + s * 32768 + n * 256 + 128 + quad * 8;
#pragma unroll
            for (int c = 0; c < 4; ++c) {
                short8 av = *(const short8*)&s_Adec[l16][128 + c*32 + quad*8];
                acc = MFMA16(av, *(const short8*)(bp + c*32), acc);
            }
            float vv[4];
#pragma unroll
            for (int rg = 0; rg < 4; ++rg) vv[rg] = acc[rg] + __shfl_xor(acc[rg], 32, 64);
            const float db = ddb[s * 128 + n];
            if (quad < 2) {
#pragma unroll
                for (int rg = 0; rg < 4; ++rg) s_hp[quad*4 + rg][n] = vv[rg] + db;
            }
        }
        __syncthreads();

        // D2: score GEMM [400,128-K] x [128,128], A = enc rows (t-major)
        {
            const int np = wv & 3, mq = wv >> 2, nb0 = np * 32;
            short8 bfr2[8];
            const u16* bp = g_ddwT + s * 32768 + (nb0 + l16) * 256 + quad * 8;
#pragma unroll
            for (int nn = 0; nn < 2; ++nn)
#pragma unroll
                for (int ks = 0; ks < 4; ++ks)
                    bfr2[nn*4+ks] = *(const short8*)(bp + nn*4096 + ks*32);
            const float dl0 = dlw[s*128 + nb0 + l16];
            const float dl1 = dlw[s*128 + nb0 + 16 + l16];
#pragma unroll 1
            for (int mt = mq; mt < 25; mt += 4) {
                const u16* ap = s_ring + (mt*16 + l16) * EP + quad * 8;
                f32x4 a0 = {0.f,0.f,0.f,0.f}, a1 = {0.f,0.f,0.f,0.f};
#pragma unroll
                for (int c = 0; c < 4; ++c) {
                    short8 av = *(const short8*)(ap + c*32);
                    a0 = MFMA16(av, bfr2[c],     a0);
                    a1 = MFMA16(av, bfr2[4 + c], a1);
                }
#pragma unroll
                for (int rg = 0; rg < 4; ++rg) {
                    int rt = mt*16 + quad*4 + rg;
                    int r  = rt & 7;                       // t-major
                    float v = tanhff(a0[rg] + s_hp[r][nb0 + l16]) * dl0
                            + tanhff(a1[rg] + s_hp[r][nb0 + 16 + l16]) * dl1;
                    v += __shfl_xor(v, 1, 64); v += __shfl_xor(v, 2, 64);
                    v += __shfl_xor(v, 4, 64); v += __shfl_xor(v, 8, 64);
                    if (l16 == 0) s_spart[np][rt] = v;
                }
            }
        }
        __syncthreads();

        // D3: softmax over t, max-free (rt = lane*8 + r, t-major)
        if (tid < 512) {
            const int r = tid >> 6;
            float ex = 0.0f;
            if (lane < LK) {
                int rt = lane * 8 + r;
                ex = __expf(s_spart[0][rt] + s_spart[1][rt] +
                            s_spart[2][rt] + s_spart[3][rt] + dlb[s]);
            }
            float sm = ex;
#pragma unroll
            for (int m = 1; m < 64; m <<= 1) sm += __shfl_xor(sm, m, 64);
            if (lane < LK) s_alpha[r][lane] = ex / sm;
        }
        __syncthreads();

        // D4: ctx = sum_t alpha * enc (fp32); store hi/lo rows
        {
            const int jd = tid & 127, r = tid >> 7;
            const u16* ep = s_ring + r * EP + jd;
            float a = 0.0f;
#pragma unroll 10
            for (int tt = 0; tt < LK; ++tt) a += s_alpha[r][tt] * b2f(ep[tt * (8*EP)]);
            u16 hi = f2b(a);
            s_Adec[r][jd]     = hi;
            s_Adec[r + 8][jd] = f2b(a - b2f(hi));
        }
        __syncthreads();

        // D5: decoder LSTM gates, K=384 lo-folded, B bf16 (g_dW)
        {
            const int nd0 = wv * 32;
            f32x4 a0 = {0.f,0.f,0.f,0.f}, a1 = {0.f,0.f,0.f,0.f};
            const u16* bp0 = g_dW + (nd0 + l16) * 384 + quad * 8;
            const u16* bp1 = bp0 + 16 * 384;
#pragma unroll
            for (int c = 0; c < 12; ++c) {
                const int g = c >> 2, o = (c & 3) * 32;
                const int aoff = (g == 0 ? 0 : 128) + o;
                const int boff = g * 128 + o;
                short8 av = *(const short8*)&s_Adec[l16][aoff + quad*8];
                a0 = MFMA16(av, *(const short8*)(bp0 + boff), a0);
                a1 = MFMA16(av, *(const short8*)(bp1 + boff), a1);
            }
            float v0[4], v1[4];
#pragma unroll
            for (int rg = 0; rg < 4; ++rg) {
                v0[rg] = a0[rg] + __shfl_xor(a0[rg], 32, 64);
                v1[rg] = a1[rg] + __shfl_xor(a1[rg], 32, 64);
            }
            if (quad < 2) {
#pragma unroll
                for (int rg = 0; rg < 4; ++rg) {
                    int r = quad*4 + rg;
                    s_g[nd0 + l16][r]      = v0[rg];
                    s_g[nd0 + 16 + l16][r] = v1[rg];
                }
            }
        }
        __syncthreads();

        // D6: gate combine + state update (hi/lo rows)
        {
            const int u = tid & 127, r = tid >> 7;
            float gi = s_g[u][r]       + s_dbias[u];
            float gf = s_g[128 + u][r] + s_dbias[128 + u];
            float gg = s_g[256 + u][r] + s_dbias[256 + u];
            float go = s_g[384 + u][r] + s_dbias[384 + u];
            float c = sigf(gf) * s_c[r][u] + sigf(gi) * tanhff(gg);
            float h = sigf(go) * tanhff(c);
            s_c[r][u] = c;
            u16 hi = f2b(h);
            s_Adec[r][128 + u]     = hi;
            s_Adec[r + 8][128 + u] = f2b(h - b2f(hi));
        }
        __syncthreads();

        // D7: head y1 = tanh(h @ fc_w + fc_b) (4 waves, K=128 lo-folded)
        if (wv < 4) {
            const int n = wv * 16 + l16;
            f32x4 acc = {0.f,0.f,0.f,0.f};
            const u16* bp = g_fcwT + s * 8192 + n * 128 + quad * 8;
#pragma unroll
            for (int c = 0; c < 4; ++c) {
                short8 av = *(const short8*)&s_Adec[l16][128 + c*32 + quad*8];
                acc = MFMA16(av, *(const short8*)(bp + c*32), acc);
            }
            float vv[4];
#pragma unroll
            for (int rg = 0; rg < 4; ++rg) vv[rg] = acc[rg] + __shfl_xor(acc[rg], 32, 64);
            const float fb = fcb[s * 64 + n];
            if (quad < 2) {
#pragma unroll
                for (int rg = 0; rg < 4; ++rg) s_y1[quad*4 + rg][n] = tanhff(vv[rg] + fb);
            }
        }
        __syncthreads();

        // D8: out = sigmoid(y1 @ out_w + out_b)
        if (tid < 512) {
            const int r = tid >> 6;
            float v = s_y1[r][lane] * ow[s * 64 + lane];
#pragma unroll
            for (int m = 1; m < 64; m <<= 1) v += __shfl_xor(v, m, 64);
            if (lane == 0) out[(b0 + r) * NOUT + s] = sigf(v + ob[s]);
        }
        __syncthreads();
    }
}

extern "C" void kernel_launch(void* const* d_in, const int* in_sizes, int n_in,
                              void* d_out, int out_size, void* d_ws, size_t ws_size,
                              hipStream_t stream) {
    const float* x    = (const float*)d_in[0];
    const float* eWih = (const float*)d_in[1];
    const float* eWhh = (const float*)d_in[2];
    const float* ebih = (const float*)d_in[3];
    const float* ebhh = (const float*)d_in[4];
    const float* aw   = (const float*)d_in[5];
    const float* ab   = (const float*)d_in[6];
    const float* dWih = (const float*)d_in[7];
    const float* dWhh = (const float*)d_in[8];
    const float* dbih = (const float*)d_in[9];
    const float* dbhh = (const float*)d_in[10];
    const float* ddw  = (const float*)d_in[11];
    const float* ddb  = (const float*)d_in[12];
    const float* dlw  = (const float*)d_in[13];
    const float* dlb  = (const float*)d_in[14];
    const float* fcw  = (const float*)d_in[15];
    const float* fcb  = (const float*)d_in[16];
    const float* ow   = (const float*)d_in[17];
    const float* ob   = (const float*)d_in[18];
    float* out = (float*)d_out;

    convert_kernel<<<LK + 512, 256, 0, stream>>>(aw, eWih, eWhh, dWih, dWhh, ddw, fcw);
    darnn_kernel<<<NWG, NTHR, 0, stream>>>(x, ab, ebih, ebhh, dbih, dbhh, ddb,
                                           dlw, dlb, fcb, ow, ob, out);
}